// Round 2
// baseline (26745.288 us; speedup 1.0000x reference)
//
#include <hip/hip_runtime.h>

#define NTHREADS 256

__device__ __forceinline__ float gelu_f(float x) {
    return 0.5f * x * (1.0f + erff(x * 0.70710678118654752440f));
}

__global__ __launch_bounds__(NTHREADS, 1)
void gno_fused(const float* __restrict__ rndata,   // [16000,64]
               const float* __restrict__ qpos,     // [100000,3]
               const float* __restrict__ latpos,   // [16000,3]
               const int*   __restrict__ edge_dst, // [E]
               const int*   __restrict__ edge_src, // [E]
               const float* __restrict__ kW0, const float* __restrict__ kb0,
               const float* __restrict__ kW1, const float* __restrict__ kb1,
               const float* __restrict__ kW2, const float* __restrict__ kb2,
               const float* __restrict__ pW1, const float* __restrict__ pb1,
               const float* __restrict__ pW2, const float* __restrict__ pb2,
               float* __restrict__ out)            // [100000,4]
{
    __shared__ float sW0[6 * 64];
    __shared__ float sW1[64 * 64];
    __shared__ float sW2[64 * 64];
    __shared__ float sb0[64], sb1[64], sb2[64];
    __shared__ float spb1[256];
    __shared__ float spW2[256 * 4];
    __shared__ float spb2[4];
    __shared__ float sdec[16 * 68];   // 16 queries x 64 channels, pad 68 to break banks

    const int tid = threadIdx.x;

    for (int i = tid; i < 6 * 64; i += NTHREADS) sW0[i] = kW0[i];
    for (int i = tid; i < 64 * 64; i += NTHREADS) { sW1[i] = kW1[i]; sW2[i] = kW2[i]; }
    if (tid < 64) { sb0[tid] = kb0[tid]; sb1[tid] = kb1[tid]; sb2[tid] = kb2[tid]; }
    spb1[tid] = pb1[tid];                      // NTHREADS == 256
    for (int i = tid; i < 256 * 4; i += NTHREADS) spW2[i] = pW2[i];
    if (tid < 4) spb2[tid] = pb2[tid];
    __syncthreads();

    const int e   = blockIdx.x * NTHREADS + tid;   // E = 1,600,000 = 6250*256 exactly
    const int src = edge_src[e];
    const int dst = edge_dst[e];

    const float ef0 = latpos[src * 3 + 0], ef1 = latpos[src * 3 + 1], ef2 = latpos[src * 3 + 2];
    const float ef3 = qpos  [dst * 3 + 0], ef4 = qpos  [dst * 3 + 1], ef5 = qpos  [dst * 3 + 2];

    float h[64], a[64];

    // ---- layer 0: [6] -> [64], GELU ----
    #pragma unroll
    for (int i4 = 0; i4 < 16; ++i4) {
        float c0 = sb0[i4 * 4 + 0], c1 = sb0[i4 * 4 + 1];
        float c2 = sb0[i4 * 4 + 2], c3 = sb0[i4 * 4 + 3];
        #pragma unroll
        for (int j = 0; j < 6; ++j) {
            const float hj = (j == 0) ? ef0 : (j == 1) ? ef1 : (j == 2) ? ef2
                           : (j == 3) ? ef3 : (j == 4) ? ef4 : ef5;
            const float4 w = *(const float4*)&sW0[j * 64 + i4 * 4];
            c0 += hj * w.x; c1 += hj * w.y; c2 += hj * w.z; c3 += hj * w.w;
        }
        h[i4 * 4 + 0] = gelu_f(c0); h[i4 * 4 + 1] = gelu_f(c1);
        h[i4 * 4 + 2] = gelu_f(c2); h[i4 * 4 + 3] = gelu_f(c3);
    }

    // ---- layer 1: [64] -> [64], GELU ----
    #pragma unroll
    for (int i = 0; i < 64; ++i) a[i] = sb1[i];
    #pragma unroll
    for (int j = 0; j < 64; ++j) {
        const float hj = h[j];
        #pragma unroll
        for (int i4 = 0; i4 < 16; ++i4) {
            const float4 w = *(const float4*)&sW1[j * 64 + i4 * 4];
            a[i4 * 4 + 0] += hj * w.x; a[i4 * 4 + 1] += hj * w.y;
            a[i4 * 4 + 2] += hj * w.z; a[i4 * 4 + 3] += hj * w.w;
        }
    }
    #pragma unroll
    for (int i = 0; i < 64; ++i) a[i] = gelu_f(a[i]);
    // h[] is dead from here; only a[64] stays live.

    // ---- layer 2 fused with rep = kern * rndata[src] and 16-edge mean ----
    const float* rn = rndata + (size_t)src * 64;
    const int sub = tid & 15;   // lane within the query's 16-edge group
    const int lq  = tid >> 4;   // local query index 0..15
    float dec0 = 0.f, dec1 = 0.f, dec2 = 0.f, dec3 = 0.f;
    #pragma unroll
    for (int i4 = 0; i4 < 16; ++i4) {
        float c0 = sb2[i4 * 4 + 0], c1 = sb2[i4 * 4 + 1];
        float c2 = sb2[i4 * 4 + 2], c3 = sb2[i4 * 4 + 3];
        #pragma unroll
        for (int j = 0; j < 64; ++j) {
            const float hj = a[j];
            const float4 w = *(const float4*)&sW2[j * 64 + i4 * 4];
            c0 += hj * w.x; c1 += hj * w.y; c2 += hj * w.z; c3 += hj * w.w;
        }
        const float4 r4 = *(const float4*)&rn[i4 * 4];
        float v0 = c0 * r4.x, v1 = c1 * r4.y, v2 = c2 * r4.z, v3 = c3 * r4.w;
        #pragma unroll
        for (int m = 1; m < 16; m <<= 1) {
            v0 += __shfl_xor(v0, m, 16);
            v1 += __shfl_xor(v1, m, 16);
            v2 += __shfl_xor(v2, m, 16);
            v3 += __shfl_xor(v3, m, 16);
        }
        if (sub == i4) { dec0 = v0 * 0.0625f; dec1 = v1 * 0.0625f;
                         dec2 = v2 * 0.0625f; dec3 = v3 * 0.0625f; }
    }
    *(float4*)&sdec[lq * 68 + sub * 4] = make_float4(dec0, dec1, dec2, dec3);
    __syncthreads();

    // ---- projection: gelu(dec @ pW1 + pb1) @ pW2 + pb2, 16 lanes per query ----
    float o0 = 0.f, o1 = 0.f, o2 = 0.f, o3 = 0.f;
    #pragma unroll
    for (int b = 0; b < 4; ++b) {
        const int u0 = sub * 4 + b * 64;          // this lane's 4 hidden units
        float s0 = spb1[u0 + 0], s1 = spb1[u0 + 1], s2 = spb1[u0 + 2], s3 = spb1[u0 + 3];
        for (int j4 = 0; j4 < 16; ++j4) {
            const float4 d4 = *(const float4*)&sdec[lq * 68 + j4 * 4];
            const float4 w0 = *(const float4*)&pW1[(j4 * 4 + 0) * 256 + u0];
            const float4 w1 = *(const float4*)&pW1[(j4 * 4 + 1) * 256 + u0];
            const float4 w2 = *(const float4*)&pW1[(j4 * 4 + 2) * 256 + u0];
            const float4 w3 = *(const float4*)&pW1[(j4 * 4 + 3) * 256 + u0];
            s0 += d4.x * w0.x + d4.y * w1.x + d4.z * w2.x + d4.w * w3.x;
            s1 += d4.x * w0.y + d4.y * w1.y + d4.z * w2.y + d4.w * w3.y;
            s2 += d4.x * w0.z + d4.y * w1.z + d4.z * w2.z + d4.w * w3.z;
            s3 += d4.x * w0.w + d4.y * w1.w + d4.z * w2.w + d4.w * w3.w;
        }
        const float g0 = gelu_f(s0), g1 = gelu_f(s1), g2 = gelu_f(s2), g3 = gelu_f(s3);
        const float4 w20 = *(const float4*)&spW2[(u0 + 0) * 4];
        const float4 w21 = *(const float4*)&spW2[(u0 + 1) * 4];
        const float4 w22 = *(const float4*)&spW2[(u0 + 2) * 4];
        const float4 w23 = *(const float4*)&spW2[(u0 + 3) * 4];
        o0 += g0 * w20.x + g1 * w21.x + g2 * w22.x + g3 * w23.x;
        o1 += g0 * w20.y + g1 * w21.y + g2 * w22.y + g3 * w23.y;
        o2 += g0 * w20.z + g1 * w21.z + g2 * w22.z + g3 * w23.z;
        o3 += g0 * w20.w + g1 * w21.w + g2 * w22.w + g3 * w23.w;
    }
    #pragma unroll
    for (int m = 1; m < 16; m <<= 1) {
        o0 += __shfl_xor(o0, m, 16);
        o1 += __shfl_xor(o1, m, 16);
        o2 += __shfl_xor(o2, m, 16);
        o3 += __shfl_xor(o3, m, 16);
    }
    if (sub == 0) {
        const int q = blockIdx.x * 16 + lq;
        *(float4*)&out[(size_t)q * 4] =
            make_float4(o0 + spb2[0], o1 + spb2[1], o2 + spb2[2], o3 + spb2[3]);
    }
}

extern "C" void kernel_launch(void* const* d_in, const int* in_sizes, int n_in,
                              void* d_out, int out_size, void* d_ws, size_t ws_size,
                              hipStream_t stream)
{
    const float* rndata = (const float*)d_in[0];
    const float* qpos   = (const float*)d_in[1];
    const float* latpos = (const float*)d_in[3];
    const int*   edge   = (const int*)d_in[5];
    const float* kW0 = (const float*)d_in[6];
    const float* kb0 = (const float*)d_in[7];
    const float* kW1 = (const float*)d_in[8];
    const float* kb1 = (const float*)d_in[9];
    const float* kW2 = (const float*)d_in[10];
    const float* kb2 = (const float*)d_in[11];
    const float* pW1 = (const float*)d_in[12];
    const float* pb1 = (const float*)d_in[13];
    const float* pW2 = (const float*)d_in[14];
    const float* pb2 = (const float*)d_in[15];
    float* out = (float*)d_out;

    const int E = in_sizes[5] / 2;          // 1,600,000
    const int nblocks = E / NTHREADS;       // 6250, exact

    gno_fused<<<nblocks, NTHREADS, 0, stream>>>(
        rndata, qpos, latpos, edge, edge + E,
        kW0, kb0, kW1, kb1, kW2, kb2, pW1, pb1, pW2, pb2, out);
}

// Round 3
// 618.529 us; speedup vs baseline: 43.2402x; 43.2402x over previous
//
#include <hip/hip_runtime.h>

#define NT 256

// exact-erf GELU via Abramowitz-Stegun 7.1.26 (|err_erf| <= 1.5e-7), fully inline
__device__ __forceinline__ float gelu_f(float x) {
    const float z = fabsf(x) * 0.70710678118654752440f;
    const float t = 1.0f / (1.0f + 0.3275911f * z);
    const float poly = t * (0.254829592f + t * (-0.284496736f + t * (1.421413741f +
                       t * (-1.453152027f + t * 1.061405429f))));
    const float e = 1.0f - poly * __expf(-z * z);
    const float s = (x >= 0.0f) ? e : -e;
    return 0.5f * x * (1.0f + s);
}

// Layout: lane bits [1:0]=p (16-channel chunk), [4:2]=kk (edge-pair), [5]=qh.
// Wave = 2 queries x 16 edges (MT=2 edges/thread). Block = 8 queries = 128 edges.
__global__ __launch_bounds__(NT, 2)
void gno_fused(const float* __restrict__ rndata,   // [16000,64]
               const float* __restrict__ qpos,     // [100000,3]
               const float* __restrict__ latpos,   // [16000,3]
               const int*   __restrict__ edge_src, // [E]
               const float* __restrict__ kW0, const float* __restrict__ kb0,
               const float* __restrict__ kW1, const float* __restrict__ kb1,
               const float* __restrict__ kW2, const float* __restrict__ kb2,
               const float* __restrict__ pW1, const float* __restrict__ pb1,
               const float* __restrict__ pW2, const float* __restrict__ pb2,
               float* __restrict__ out)            // [100000,4]
{
    __shared__ float sW0[6 * 64];
    __shared__ float sW1[64 * 64];
    __shared__ float sW2[64 * 64];
    __shared__ float sb0[64], sb1[64], sb2[64];
    __shared__ float spb1[256];
    __shared__ float spW2[256 * 4];
    __shared__ float spb2[4];
    __shared__ float sdec[8 * 68];

    const int tid = threadIdx.x;

    for (int i = tid; i < 6 * 64; i += NT) sW0[i] = kW0[i];
    for (int i = tid; i < 64 * 64; i += NT) { sW1[i] = kW1[i]; sW2[i] = kW2[i]; }
    if (tid < 64) { sb0[tid] = kb0[tid]; sb1[tid] = kb1[tid]; sb2[tid] = kb2[tid]; }
    spb1[tid] = pb1[tid];
    for (int i = tid; i < 256 * 4; i += NT) spW2[i] = pW2[i];
    if (tid < 4) spb2[tid] = pb2[tid];
    __syncthreads();

    const int lane  = tid & 63;
    const int p     = lane & 3;
    const int p16   = p * 16;
    const int kk    = (lane >> 2) & 7;
    const int lq    = tid >> 5;                 // query in block, 0..7
    const int q     = blockIdx.x * 8 + lq;
    const int lbase = lane & ~3;

    const int e0 = q * 16 + kk * 2;             // dst[e] == e/16 == q (fixed degree)
    const int2 sp = *(const int2*)&edge_src[e0];
    const int src0 = sp.x, src1 = sp.y;

    float ef[2][6];
    ef[0][0] = latpos[src0 * 3 + 0]; ef[0][1] = latpos[src0 * 3 + 1]; ef[0][2] = latpos[src0 * 3 + 2];
    ef[1][0] = latpos[src1 * 3 + 0]; ef[1][1] = latpos[src1 * 3 + 1]; ef[1][2] = latpos[src1 * 3 + 2];
    const float qx = qpos[q * 3 + 0], qy = qpos[q * 3 + 1], qz = qpos[q * 3 + 2];
    ef[0][3] = qx; ef[0][4] = qy; ef[0][5] = qz;
    ef[1][3] = qx; ef[1][4] = qy; ef[1][5] = qz;

    float hreg[2][16];
    float acc[2][16];

    // ---- layer 0: [6] -> my 16 channels, GELU ----
    #pragma unroll
    for (int m = 0; m < 2; ++m) {
        float c[16];
        #pragma unroll
        for (int c4 = 0; c4 < 4; ++c4) {
            const float4 b = *(const float4*)&sb0[p16 + c4 * 4];
            c[c4*4+0] = b.x; c[c4*4+1] = b.y; c[c4*4+2] = b.z; c[c4*4+3] = b.w;
        }
        #pragma unroll
        for (int j = 0; j < 6; ++j) {
            const float hj = ef[m][j];
            #pragma unroll
            for (int c4 = 0; c4 < 4; ++c4) {
                const float4 w = *(const float4*)&sW0[j * 64 + p16 + c4 * 4];
                c[c4*4+0] += hj * w.x; c[c4*4+1] += hj * w.y;
                c[c4*4+2] += hj * w.z; c[c4*4+3] += hj * w.w;
            }
        }
        #pragma unroll
        for (int i = 0; i < 16; ++i) hreg[m][i] = gelu_f(c[i]);
    }

    // ---- layer 1: 64 -> my 16, GELU.  h[j] broadcast from lane (lbase + j>>4) ----
    #pragma unroll
    for (int m = 0; m < 2; ++m)
        #pragma unroll
        for (int c4 = 0; c4 < 4; ++c4) {
            const float4 b = *(const float4*)&sb1[p16 + c4 * 4];
            acc[m][c4*4+0] = b.x; acc[m][c4*4+1] = b.y;
            acc[m][c4*4+2] = b.z; acc[m][c4*4+3] = b.w;
        }
    #pragma unroll 1
    for (int j1 = 0; j1 < 4; ++j1) {
        #pragma unroll
        for (int j0 = 0; j0 < 16; ++j0) {
            const int j = j1 * 16 + j0;
            const float h0j = __shfl(hreg[0][j0], lbase + j1);
            const float h1j = __shfl(hreg[1][j0], lbase + j1);
            #pragma unroll
            for (int c4 = 0; c4 < 4; ++c4) {
                const float4 w = *(const float4*)&sW1[j * 64 + p16 + c4 * 4];
                acc[0][c4*4+0] += h0j * w.x; acc[0][c4*4+1] += h0j * w.y;
                acc[0][c4*4+2] += h0j * w.z; acc[0][c4*4+3] += h0j * w.w;
                acc[1][c4*4+0] += h1j * w.x; acc[1][c4*4+1] += h1j * w.y;
                acc[1][c4*4+2] += h1j * w.z; acc[1][c4*4+3] += h1j * w.w;
            }
        }
    }
    #pragma unroll
    for (int m = 0; m < 2; ++m)
        #pragma unroll
        for (int i = 0; i < 16; ++i) hreg[m][i] = gelu_f(acc[m][i]);

    // ---- layer 2: 64 -> my 16, linear (kern) ----
    #pragma unroll
    for (int m = 0; m < 2; ++m)
        #pragma unroll
        for (int c4 = 0; c4 < 4; ++c4) {
            const float4 b = *(const float4*)&sb2[p16 + c4 * 4];
            acc[m][c4*4+0] = b.x; acc[m][c4*4+1] = b.y;
            acc[m][c4*4+2] = b.z; acc[m][c4*4+3] = b.w;
        }
    #pragma unroll 1
    for (int j1 = 0; j1 < 4; ++j1) {
        #pragma unroll
        for (int j0 = 0; j0 < 16; ++j0) {
            const int j = j1 * 16 + j0;
            const float h0j = __shfl(hreg[0][j0], lbase + j1);
            const float h1j = __shfl(hreg[1][j0], lbase + j1);
            #pragma unroll
            for (int c4 = 0; c4 < 4; ++c4) {
                const float4 w = *(const float4*)&sW2[j * 64 + p16 + c4 * 4];
                acc[0][c4*4+0] += h0j * w.x; acc[0][c4*4+1] += h0j * w.y;
                acc[0][c4*4+2] += h0j * w.z; acc[0][c4*4+3] += h0j * w.w;
                acc[1][c4*4+0] += h1j * w.x; acc[1][c4*4+1] += h1j * w.y;
                acc[1][c4*4+2] += h1j * w.z; acc[1][c4*4+3] += h1j * w.w;
            }
        }
    }

    // ---- rep = kern * rndata[src]; sum 2 local edges, then reduce over kk ----
    const float* rn0 = rndata + (size_t)src0 * 64 + p16;
    const float* rn1 = rndata + (size_t)src1 * 64 + p16;
    float v[16];
    #pragma unroll
    for (int c4 = 0; c4 < 4; ++c4) {
        const float4 r0 = *(const float4*)&rn0[c4 * 4];
        const float4 r1 = *(const float4*)&rn1[c4 * 4];
        v[c4*4+0] = acc[0][c4*4+0] * r0.x + acc[1][c4*4+0] * r1.x;
        v[c4*4+1] = acc[0][c4*4+1] * r0.y + acc[1][c4*4+1] * r1.y;
        v[c4*4+2] = acc[0][c4*4+2] * r0.z + acc[1][c4*4+2] * r1.z;
        v[c4*4+3] = acc[0][c4*4+3] * r0.w + acc[1][c4*4+3] * r1.w;
    }
    #pragma unroll
    for (int i = 0; i < 16; ++i) {
        v[i] += __shfl_xor(v[i], 4);
        v[i] += __shfl_xor(v[i], 8);
        v[i] += __shfl_xor(v[i], 16);
    }
    if (kk == 0) {
        #pragma unroll
        for (int c4 = 0; c4 < 4; ++c4)
            *(float4*)&sdec[lq * 68 + p16 + c4 * 4] =
                make_float4(v[c4*4+0] * 0.0625f, v[c4*4+1] * 0.0625f,
                            v[c4*4+2] * 0.0625f, v[c4*4+3] * 0.0625f);
    }
    __syncthreads();

    // ---- projection: 32 lanes per query, 8 hidden units per lane ----
    const int ln = tid & 31;
    const int u0 = ln * 8;
    float s[8];
    #pragma unroll
    for (int i = 0; i < 8; ++i) s[i] = spb1[u0 + i];
    #pragma unroll 4
    for (int j = 0; j < 64; ++j) {
        const float dj = sdec[lq * 68 + j];
        const float4 wA = *(const float4*)&pW1[j * 256 + u0];
        const float4 wB = *(const float4*)&pW1[j * 256 + u0 + 4];
        s[0] += dj * wA.x; s[1] += dj * wA.y; s[2] += dj * wA.z; s[3] += dj * wA.w;
        s[4] += dj * wB.x; s[5] += dj * wB.y; s[6] += dj * wB.z; s[7] += dj * wB.w;
    }
    float o0 = 0.f, o1 = 0.f, o2 = 0.f, o3 = 0.f;
    #pragma unroll
    for (int i = 0; i < 8; ++i) {
        const float g = gelu_f(s[i]);
        const float4 w2 = *(const float4*)&spW2[(u0 + i) * 4];
        o0 += g * w2.x; o1 += g * w2.y; o2 += g * w2.z; o3 += g * w2.w;
    }
    #pragma unroll
    for (int m = 1; m <= 16; m <<= 1) {
        o0 += __shfl_xor(o0, m); o1 += __shfl_xor(o1, m);
        o2 += __shfl_xor(o2, m); o3 += __shfl_xor(o3, m);
    }
    if (ln == 0) {
        *(float4*)&out[(size_t)q * 4] =
            make_float4(o0 + spb2[0], o1 + spb2[1], o2 + spb2[2], o3 + spb2[3]);
    }
}

extern "C" void kernel_launch(void* const* d_in, const int* in_sizes, int n_in,
                              void* d_out, int out_size, void* d_ws, size_t ws_size,
                              hipStream_t stream)
{
    const float* rndata = (const float*)d_in[0];
    const float* qpos   = (const float*)d_in[1];
    const float* latpos = (const float*)d_in[3];
    const int*   edge   = (const int*)d_in[5];
    const float* kW0 = (const float*)d_in[6];
    const float* kb0 = (const float*)d_in[7];
    const float* kW1 = (const float*)d_in[8];
    const float* kb1 = (const float*)d_in[9];
    const float* kW2 = (const float*)d_in[10];
    const float* kb2 = (const float*)d_in[11];
    const float* pW1 = (const float*)d_in[12];
    const float* pb1 = (const float*)d_in[13];
    const float* pW2 = (const float*)d_in[14];
    const float* pb2 = (const float*)d_in[15];
    float* out = (float*)d_out;

    const int E = in_sizes[5] / 2;          // 1,600,000
    const int nblocks = E / 128;            // 12,500 (8 queries / block)

    gno_fused<<<nblocks, NT, 0, stream>>>(
        rndata, qpos, latpos, edge + E,
        kW0, kb0, kW1, kb1, kW2, kb2, pW1, pb1, pW2, pb2, out);
}

// Round 4
// 371.797 us; speedup vs baseline: 71.9352x; 1.6636x over previous
//
#include <hip/hip_runtime.h>

typedef __attribute__((ext_vector_type(8))) __bf16 bf16x8;
typedef __attribute__((ext_vector_type(4))) float f32x4;
typedef __attribute__((ext_vector_type(4))) unsigned int u32x4;

union FragU { u32x4 u; bf16x8 b; };
union BfBits { __bf16 b; unsigned short s; };

#define MFMA16(A, B, C) __builtin_amdgcn_mfma_f32_16x16x32_bf16((A), (B), (C), 0, 0, 0)

__device__ __forceinline__ float gelu_f(float x) {
    const float z = fabsf(x) * 0.70710678118654752440f;
    const float t = 1.0f / (1.0f + 0.3275911f * z);
    const float poly = t * (0.254829592f + t * (-0.284496736f + t * (1.421413741f +
                       t * (-1.453152027f + t * 1.061405429f))));
    const float e = 1.0f - poly * __expf(-z * z);
    const float s = (x >= 0.0f) ? e : -e;
    return 0.5f * x * (1.0f + s);
}

// ---------------------------------------------------------------------------
// Prep: swizzle W0 (+b0 at k==6), W1, W2 into MFMA B-fragment order, bf16 hi/lo.
// Fragment elem (lane, i) = W[k = ks*32 + (lane>>4)*8 + i][n = nt*16 + (lane&15)]
// ws layout (ushort):
//   [0,4096)       W0f [nt][hl][lane][8]
//   [4096,12288)   W1f [ks][nt][hl][lane][8]
//   [12288,20480)  W2f [ks][nt][hl][lane][8]
// ---------------------------------------------------------------------------
__global__ __launch_bounds__(256)
void prep_frags(const float* __restrict__ kW0, const float* __restrict__ kb0,
                const float* __restrict__ kW1, const float* __restrict__ kW2,
                unsigned short* __restrict__ wsf)
{
    const int idx  = blockIdx.x * 256 + threadIdx.x;   // 0..20479
    const int i    = idx & 7;
    const int lane = (idx >> 3) & 63;
    float val;
    int hl;
    if (idx < 4096) {
        const int rest = idx >> 9;           // nt*2+hl
        hl = rest & 1;
        const int nt = rest >> 1;
        const int k = (lane >> 4) * 8 + i;
        const int n = nt * 16 + (lane & 15);
        val = (k < 6) ? kW0[k * 64 + n] : (k == 6 ? kb0[n] : 0.0f);
    } else if (idx < 12288) {
        const int rest = (idx - 4096) >> 9;  // (ks*4+nt)*2+hl
        hl = rest & 1;
        const int ntks = rest >> 1;
        const int nt = ntks & 3, ks = ntks >> 2;
        const int k = ks * 32 + (lane >> 4) * 8 + i;
        const int n = nt * 16 + (lane & 15);
        val = kW1[k * 64 + n];
    } else {
        const int rest = (idx - 12288) >> 9;
        hl = rest & 1;
        const int ntks = rest >> 1;
        const int nt = ntks & 3, ks = ntks >> 2;
        const int k = ks * 32 + (lane >> 4) * 8 + i;
        const int n = nt * 16 + (lane & 15);
        val = kW2[k * 64 + n];
    }
    BfBits hi; hi.b = (__bf16)val;
    unsigned short ob;
    if (hl == 0) ob = hi.s;
    else { BfBits lo; lo.b = (__bf16)(val - (float)hi.b); ob = lo.s; }
    wsf[idx] = ob;
}

// ---------------------------------------------------------------------------
// Main: 1 wave = 1 query (16 edges) per step, 4 queries per wave, 4 waves/block.
// D-layout (verified m89): col = lane&15, row = (lane>>4)*4 + reg.
// A-layout (assumed):      row = lane&15, k  = (lane>>4)*8 + i.
// ---------------------------------------------------------------------------
__global__ __launch_bounds__(256, 2)
void gno_mfma(const float* __restrict__ rndata,   // [16000,64]
              const float* __restrict__ qpos,     // [100000,3]
              const float* __restrict__ latpos,   // [16000,3]
              const int*   __restrict__ edge_src, // [E]
              const float* __restrict__ kb1, const float* __restrict__ kb2,
              const float* __restrict__ pW1, const float* __restrict__ pb1,
              const float* __restrict__ pW2, const float* __restrict__ pb2,
              const unsigned short* __restrict__ wsf,
              float* __restrict__ out)            // [100000,4]
{
    __shared__ __align__(16) float sH[4][16][68];
    __shared__ float sdec[16][65];
    __shared__ float sb1[64], sb2[64];

    const int tid = threadIdx.x;
    if (tid < 64) { sb1[tid] = kb1[tid]; sb2[tid] = kb2[tid]; }
    __syncthreads();

    const int l   = tid & 63;
    const int w   = tid >> 6;
    const int r15 = l & 15;
    const int g   = l >> 4;
    const int qbase = blockIdx.x * 16 + w * 4;

    const u32x4* wv = (const u32x4*)wsf;   // frag f at uint4 index: W0 f, W1 512+f, W2 1536+f
    float (*myH)[68] = sH[w];

    #pragma unroll 1
    for (int t = 0; t < 4; ++t) {
        const int q = qbase + t;
        const int srcv = edge_src[q * 16 + r15];

        // ---- layer 0: A-frag from coords (lanes k-group 0 only), bias via k==6 ----
        float av[8];
        av[0] = latpos[srcv * 3 + 0]; av[1] = latpos[srcv * 3 + 1]; av[2] = latpos[srcv * 3 + 2];
        av[3] = qpos[q * 3 + 0];      av[4] = qpos[q * 3 + 1];      av[5] = qpos[q * 3 + 2];
        av[6] = 1.0f; av[7] = 0.0f;
        bf16x8 a0h, a0l;
        #pragma unroll
        for (int i = 0; i < 8; ++i) {
            const float x = (g == 0) ? av[i] : 0.0f;
            const __bf16 hb = (__bf16)x;
            a0h[i] = hb; a0l[i] = (__bf16)(x - (float)hb);
        }
        #pragma unroll
        for (int nt = 0; nt < 4; ++nt) {
            FragU wh, wl;
            wh.u = wv[(nt * 2 + 0) * 64 + l];
            wl.u = wv[(nt * 2 + 1) * 64 + l];
            f32x4 c = {0.f, 0.f, 0.f, 0.f};
            c = MFMA16(a0h, wh.b, c);
            c = MFMA16(a0l, wh.b, c);
            c = MFMA16(a0h, wl.b, c);
            #pragma unroll
            for (int j = 0; j < 4; ++j)
                myH[g * 4 + j][nt * 16 + r15] = gelu_f(c[j]);
        }

        // ---- layer 1: A from sH (row=l&15, k=g*8+i), GELU, overwrite sH ----
        bf16x8 a1h[2], a1l[2];
        #pragma unroll
        for (int ks = 0; ks < 2; ++ks) {
            const float* p = &myH[r15][ks * 32 + g * 8];
            const float4 xa = *(const float4*)p;
            const float4 xb = *(const float4*)(p + 4);
            const float xs[8] = {xa.x, xa.y, xa.z, xa.w, xb.x, xb.y, xb.z, xb.w};
            #pragma unroll
            for (int i = 0; i < 8; ++i) {
                const __bf16 hb = (__bf16)xs[i];
                a1h[ks][i] = hb; a1l[ks][i] = (__bf16)(xs[i] - (float)hb);
            }
        }
        #pragma unroll
        for (int nt = 0; nt < 4; ++nt) {
            const float bv = sb1[nt * 16 + r15];
            f32x4 c = {bv, bv, bv, bv};
            #pragma unroll
            for (int ks = 0; ks < 2; ++ks) {
                FragU wh, wl;
                wh.u = wv[512 + ((ks * 4 + nt) * 2 + 0) * 64 + l];
                wl.u = wv[512 + ((ks * 4 + nt) * 2 + 1) * 64 + l];
                c = MFMA16(a1h[ks], wh.b, c);
                c = MFMA16(a1l[ks], wh.b, c);
                c = MFMA16(a1h[ks], wl.b, c);
            }
            #pragma unroll
            for (int j = 0; j < 4; ++j)
                myH[g * 4 + j][nt * 16 + r15] = gelu_f(c[j]);
        }

        // ---- layer 2 (+ rep*rndata + 16-edge mean) ----
        bf16x8 a2h[2], a2l[2];
        #pragma unroll
        for (int ks = 0; ks < 2; ++ks) {
            const float* p = &myH[r15][ks * 32 + g * 8];
            const float4 xa = *(const float4*)p;
            const float4 xb = *(const float4*)(p + 4);
            const float xs[8] = {xa.x, xa.y, xa.z, xa.w, xb.x, xb.y, xb.z, xb.w};
            #pragma unroll
            for (int i = 0; i < 8; ++i) {
                const __bf16 hb = (__bf16)xs[i];
                a2h[ks][i] = hb; a2l[ks][i] = (__bf16)(xs[i] - (float)hb);
            }
        }
        int se[4];
        #pragma unroll
        for (int r = 0; r < 4; ++r) se[r] = __shfl(srcv, g * 4 + r);
        #pragma unroll
        for (int nt = 0; nt < 4; ++nt) {
            const float bv = sb2[nt * 16 + r15];
            f32x4 c = {bv, bv, bv, bv};
            #pragma unroll
            for (int ks = 0; ks < 2; ++ks) {
                FragU wh, wl;
                wh.u = wv[1536 + ((ks * 4 + nt) * 2 + 0) * 64 + l];
                wl.u = wv[1536 + ((ks * 4 + nt) * 2 + 1) * 64 + l];
                c = MFMA16(a2h[ks], wh.b, c);
                c = MFMA16(a2l[ks], wh.b, c);
                c = MFMA16(a2h[ks], wl.b, c);
            }
            float v = 0.0f;
            #pragma unroll
            for (int r = 0; r < 4; ++r) {
                const float rnd = rndata[(size_t)se[r] * 64 + nt * 16 + r15];
                v += c[r] * rnd;    // c[r] is edge (g*4+r), channel nt*16+r15
            }
            v += __shfl_xor(v, 16);
            v += __shfl_xor(v, 32);
            if (l < 16) sdec[w * 4 + t][nt * 16 + l] = v * 0.0625f;
        }
    }

    // ---- projection (wave-private): lane owns units 4l..4l+3, 4 queries ----
    float s[4][4];
    #pragma unroll
    for (int t = 0; t < 4; ++t)
        #pragma unroll
        for (int i = 0; i < 4; ++i) s[t][i] = 0.0f;

    const float4* pw1v = (const float4*)pW1;
    #pragma unroll 4
    for (int j = 0; j < 64; ++j) {
        const float4 w4 = pw1v[j * 64 + l];
        #pragma unroll
        for (int t = 0; t < 4; ++t) {
            const float dj = sdec[w * 4 + t][j];
            s[t][0] += dj * w4.x; s[t][1] += dj * w4.y;
            s[t][2] += dj * w4.z; s[t][3] += dj * w4.w;
        }
    }
    const float4 pb1q = *(const float4*)&pb1[l * 4];
    const float pb1a[4] = {pb1q.x, pb1q.y, pb1q.z, pb1q.w};
    float o[4][4];
    #pragma unroll
    for (int t = 0; t < 4; ++t)
        #pragma unroll
        for (int c = 0; c < 4; ++c) o[t][c] = 0.0f;
    #pragma unroll
    for (int i = 0; i < 4; ++i) {
        const float4 w2 = *(const float4*)&pW2[(l * 4 + i) * 4];
        #pragma unroll
        for (int t = 0; t < 4; ++t) {
            const float gv = gelu_f(s[t][i] + pb1a[i]);
            o[t][0] += gv * w2.x; o[t][1] += gv * w2.y;
            o[t][2] += gv * w2.z; o[t][3] += gv * w2.w;
        }
    }
    #pragma unroll
    for (int m = 1; m < 64; m <<= 1)
        #pragma unroll
        for (int t = 0; t < 4; ++t) {
            o[t][0] += __shfl_xor(o[t][0], m);
            o[t][1] += __shfl_xor(o[t][1], m);
            o[t][2] += __shfl_xor(o[t][2], m);
            o[t][3] += __shfl_xor(o[t][3], m);
        }
    if (l == 0) {
        const float4 pb2v = *(const float4*)pb2;
        #pragma unroll
        for (int t = 0; t < 4; ++t)
            *(float4*)&out[(size_t)(qbase + t) * 4] =
                make_float4(o[t][0] + pb2v.x, o[t][1] + pb2v.y,
                            o[t][2] + pb2v.z, o[t][3] + pb2v.w);
    }
}

extern "C" void kernel_launch(void* const* d_in, const int* in_sizes, int n_in,
                              void* d_out, int out_size, void* d_ws, size_t ws_size,
                              hipStream_t stream)
{
    const float* rndata = (const float*)d_in[0];
    const float* qpos   = (const float*)d_in[1];
    const float* latpos = (const float*)d_in[3];
    const int*   edge   = (const int*)d_in[5];
    const float* kW0 = (const float*)d_in[6];
    const float* kb0 = (const float*)d_in[7];
    const float* kW1 = (const float*)d_in[8];
    const float* kb1 = (const float*)d_in[9];
    const float* kW2 = (const float*)d_in[10];
    const float* kb2 = (const float*)d_in[11];
    const float* pW1 = (const float*)d_in[12];
    const float* pb1 = (const float*)d_in[13];
    const float* pW2 = (const float*)d_in[14];
    const float* pb2 = (const float*)d_in[15];
    float* out = (float*)d_out;

    const int E  = in_sizes[5] / 2;   // 1,600,000
    const int Nq = out_size / 4;      // 100,000

    prep_frags<<<80, 256, 0, stream>>>(kW0, kb0, kW1, kW2, (unsigned short*)d_ws);
    gno_mfma<<<Nq / 16, 256, 0, stream>>>(
        rndata, qpos, latpos, edge + E,
        kb1, kb2, pW1, pb1, pW2, pb2,
        (const unsigned short*)d_ws, out);
}

// Round 5
// 325.027 us; speedup vs baseline: 82.2864x; 1.1439x over previous
//
#include <hip/hip_runtime.h>

typedef __attribute__((ext_vector_type(8))) __bf16 bf16x8;
typedef __attribute__((ext_vector_type(4))) float f32x4;
typedef __attribute__((ext_vector_type(4))) unsigned int u32x4;

union FragU { u32x4 u; bf16x8 b; };
union BfBits { __bf16 b; unsigned short s; };

#define MFMA16(A, B, C) __builtin_amdgcn_mfma_f32_16x16x32_bf16((A), (B), (C), 0, 0, 0)

__device__ __forceinline__ float gelu_f(float x) {
    const float z = fabsf(x) * 0.70710678118654752440f;
    const float t = 1.0f / (1.0f + 0.3275911f * z);
    const float poly = t * (0.254829592f + t * (-0.284496736f + t * (1.421413741f +
                       t * (-1.453152027f + t * 1.061405429f))));
    const float e = 1.0f - poly * __expf(-z * z);
    const float s = (x >= 0.0f) ? e : -e;
    return 0.5f * x * (1.0f + s);
}

// ---------------------------------------------------------------------------
// Prep: swizzle weights into MFMA B-fragment order, bf16 hi/lo planes.
// Fragment elem (lane, i) = W[k = ks*32 + (lane>>4)*8 + i][n = nt*16 + (lane&15)]
// ws layout (ushort):
//   [0,4096)        W0f  [nt4][hl2][lane][8]   (b0 folded in at k==6)
//   [4096,12288)    W1f  [ks2][nt4][hl2][lane][8]
//   [12288,20480)   W2f  [ks2][nt4][hl2][lane][8]
//   [20480,53248)   pW1f [ks2][nt16][hl2][lane][8]
// ---------------------------------------------------------------------------
__global__ __launch_bounds__(256)
void prep_frags(const float* __restrict__ kW0, const float* __restrict__ kb0,
                const float* __restrict__ kW1, const float* __restrict__ kW2,
                const float* __restrict__ pW1,
                unsigned short* __restrict__ wsf)
{
    const int idx  = blockIdx.x * 256 + threadIdx.x;   // 0..53247
    const int i    = idx & 7;
    const int lane = (idx >> 3) & 63;
    float val;
    int hl;
    if (idx < 4096) {
        const int rest = idx >> 9;           // nt*2+hl
        hl = rest & 1;
        const int nt = rest >> 1;
        const int k = (lane >> 4) * 8 + i;
        const int n = nt * 16 + (lane & 15);
        val = (k < 6) ? kW0[k * 64 + n] : (k == 6 ? kb0[n] : 0.0f);
    } else if (idx < 12288) {
        const int rest = (idx - 4096) >> 9;  // (ks*4+nt)*2+hl
        hl = rest & 1;
        const int ntks = rest >> 1;
        const int nt = ntks & 3, ks = ntks >> 2;
        const int k = ks * 32 + (lane >> 4) * 8 + i;
        const int n = nt * 16 + (lane & 15);
        val = kW1[k * 64 + n];
    } else if (idx < 20480) {
        const int rest = (idx - 12288) >> 9;
        hl = rest & 1;
        const int ntks = rest >> 1;
        const int nt = ntks & 3, ks = ntks >> 2;
        const int k = ks * 32 + (lane >> 4) * 8 + i;
        const int n = nt * 16 + (lane & 15);
        val = kW2[k * 64 + n];
    } else {
        const int rest = (idx - 20480) >> 9; // (ks*16+nt)*2+hl
        hl = rest & 1;
        const int ntks = rest >> 1;
        const int nt = ntks & 15, ks = ntks >> 4;
        const int k = ks * 32 + (lane >> 4) * 8 + i;
        const int n = nt * 16 + (lane & 15);
        val = pW1[k * 256 + n];
    }
    BfBits hi; hi.b = (__bf16)val;
    unsigned short ob;
    if (hl == 0) ob = hi.s;
    else { BfBits lo; lo.b = (__bf16)(val - (float)hi.b); ob = lo.s; }
    wsf[idx] = ob;
}

// ---------------------------------------------------------------------------
// Main: wave = 1 query (16 edges) per t-step, 4 queries/wave, 4 waves/block.
// Block of 16 queries then does the projection as one M=16 MFMA tile.
// D-layout: col = lane&15, row = (lane>>4)*4 + reg.
// A-layout: row = lane&15, k  = (lane>>4)*8 + i.
// ---------------------------------------------------------------------------
__global__ __launch_bounds__(256, 2)
void gno_mfma(const float* __restrict__ rndata,   // [16000,64]
              const float* __restrict__ qpos,     // [100000,3]
              const float* __restrict__ latpos,   // [16000,3]
              const int*   __restrict__ edge_src, // [E]
              const float* __restrict__ kb1, const float* __restrict__ kb2,
              const float* __restrict__ pb1,
              const float* __restrict__ pW2, const float* __restrict__ pb2,
              const unsigned short* __restrict__ wsf,
              float* __restrict__ out)            // [100000,4]
{
    __shared__ __align__(16) float sH[4][16][68];
    __shared__ __align__(16) float sdec[16][65];
    __shared__ float spart[4][16][4];
    __shared__ float sb1[64], sb2[64];

    const int tid = threadIdx.x;
    if (tid < 64) { sb1[tid] = kb1[tid]; sb2[tid] = kb2[tid]; }
    __syncthreads();

    const int l   = tid & 63;
    const int w   = tid >> 6;
    const int r15 = l & 15;
    const int g   = l >> 4;
    const int qbase = blockIdx.x * 16 + w * 4;

    const u32x4* wv = (const u32x4*)wsf;   // u32x4 idx: W0 f, W1 512+f, W2 1536+f, pW1 2560+f
    float (*myH)[68] = sH[w];

    #pragma unroll 1
    for (int t = 0; t < 4; ++t) {
        const int q = qbase + t;
        const int srcv = edge_src[q * 16 + r15];

        // ---- layer 0: A-frag from coords (k-group 0 only), bias via k==6 ----
        float av[8];
        av[0] = latpos[srcv * 3 + 0]; av[1] = latpos[srcv * 3 + 1]; av[2] = latpos[srcv * 3 + 2];
        av[3] = qpos[q * 3 + 0];      av[4] = qpos[q * 3 + 1];      av[5] = qpos[q * 3 + 2];
        av[6] = 1.0f; av[7] = 0.0f;
        bf16x8 a0h, a0l;
        #pragma unroll
        for (int i = 0; i < 8; ++i) {
            const float x = (g == 0) ? av[i] : 0.0f;
            const __bf16 hb = (__bf16)x;
            a0h[i] = hb; a0l[i] = (__bf16)(x - (float)hb);
        }
        #pragma unroll
        for (int nt = 0; nt < 4; ++nt) {
            FragU wh, wl;
            wh.u = wv[(nt * 2 + 0) * 64 + l];
            wl.u = wv[(nt * 2 + 1) * 64 + l];
            f32x4 c = {0.f, 0.f, 0.f, 0.f};
            c = MFMA16(a0h, wh.b, c);
            c = MFMA16(a0l, wh.b, c);
            c = MFMA16(a0h, wl.b, c);
            #pragma unroll
            for (int j = 0; j < 4; ++j)
                myH[g * 4 + j][nt * 16 + r15] = gelu_f(c[j]);
        }

        // ---- layer 1: A from sH, GELU, overwrite sH ----
        bf16x8 a1h[2], a1l[2];
        #pragma unroll
        for (int ks = 0; ks < 2; ++ks) {
            const float* p = &myH[r15][ks * 32 + g * 8];
            const float4 xa = *(const float4*)p;
            const float4 xb = *(const float4*)(p + 4);
            const float xs[8] = {xa.x, xa.y, xa.z, xa.w, xb.x, xb.y, xb.z, xb.w};
            #pragma unroll
            for (int i = 0; i < 8; ++i) {
                const __bf16 hb = (__bf16)xs[i];
                a1h[ks][i] = hb; a1l[ks][i] = (__bf16)(xs[i] - (float)hb);
            }
        }
        #pragma unroll
        for (int nt = 0; nt < 4; ++nt) {
            const float bv = sb1[nt * 16 + r15];
            f32x4 c = {bv, bv, bv, bv};
            #pragma unroll
            for (int ks = 0; ks < 2; ++ks) {
                FragU wh, wl;
                wh.u = wv[512 + ((ks * 4 + nt) * 2 + 0) * 64 + l];
                wl.u = wv[512 + ((ks * 4 + nt) * 2 + 1) * 64 + l];
                c = MFMA16(a1h[ks], wh.b, c);
                c = MFMA16(a1l[ks], wh.b, c);
                c = MFMA16(a1h[ks], wl.b, c);
            }
            #pragma unroll
            for (int j = 0; j < 4; ++j)
                myH[g * 4 + j][nt * 16 + r15] = gelu_f(c[j]);
        }

        // ---- layer 2 (+ rep*rndata + 16-edge mean) ----
        bf16x8 a2h[2], a2l[2];
        #pragma unroll
        for (int ks = 0; ks < 2; ++ks) {
            const float* p = &myH[r15][ks * 32 + g * 8];
            const float4 xa = *(const float4*)p;
            const float4 xb = *(const float4*)(p + 4);
            const float xs[8] = {xa.x, xa.y, xa.z, xa.w, xb.x, xb.y, xb.z, xb.w};
            #pragma unroll
            for (int i = 0; i < 8; ++i) {
                const __bf16 hb = (__bf16)xs[i];
                a2h[ks][i] = hb; a2l[ks][i] = (__bf16)(xs[i] - (float)hb);
            }
        }
        int se[4];
        #pragma unroll
        for (int r = 0; r < 4; ++r) se[r] = __shfl(srcv, g * 4 + r);
        #pragma unroll
        for (int nt = 0; nt < 4; ++nt) {
            const float bv = sb2[nt * 16 + r15];
            f32x4 c = {bv, bv, bv, bv};
            #pragma unroll
            for (int ks = 0; ks < 2; ++ks) {
                FragU wh, wl;
                wh.u = wv[1536 + ((ks * 4 + nt) * 2 + 0) * 64 + l];
                wl.u = wv[1536 + ((ks * 4 + nt) * 2 + 1) * 64 + l];
                c = MFMA16(a2h[ks], wh.b, c);
                c = MFMA16(a2l[ks], wh.b, c);
                c = MFMA16(a2h[ks], wl.b, c);
            }
            float v = 0.0f;
            #pragma unroll
            for (int r = 0; r < 4; ++r) {
                const float rnd = rndata[(size_t)se[r] * 64 + nt * 16 + r15];
                v += c[r] * rnd;    // c[r] is edge (g*4+r), channel nt*16+r15
            }
            v += __shfl_xor(v, 16);
            v += __shfl_xor(v, 32);
            if (l < 16) sdec[w * 4 + t][nt * 16 + l] = v * 0.0625f;
        }
    }

    // ---- projection via MFMA: 16 block-queries = one M=16 tile ----
    __syncthreads();

    bf16x8 pah[2], pal[2];
    #pragma unroll
    for (int ks = 0; ks < 2; ++ks) {
        const float* p = &sdec[r15][ks * 32 + g * 8];
        const float4 xa = *(const float4*)p;
        const float4 xb = *(const float4*)(p + 4);
        const float xs[8] = {xa.x, xa.y, xa.z, xa.w, xb.x, xb.y, xb.z, xb.w};
        #pragma unroll
        for (int i = 0; i < 8; ++i) {
            const __bf16 hb = (__bf16)xs[i];
            pah[ks][i] = hb; pal[ks][i] = (__bf16)(xs[i] - (float)hb);
        }
    }

    float o[4][4];
    #pragma unroll
    for (int j = 0; j < 4; ++j)
        #pragma unroll
        for (int cc = 0; cc < 4; ++cc) o[j][cc] = 0.0f;

    #pragma unroll
    for (int ntl = 0; ntl < 4; ++ntl) {
        const int ntg = w * 4 + ntl;          // global 16-unit tile, 0..15
        f32x4 c = {0.f, 0.f, 0.f, 0.f};
        #pragma unroll
        for (int ks = 0; ks < 2; ++ks) {
            FragU wh, wl;
            wh.u = wv[2560 + ((ks * 16 + ntg) * 2 + 0) * 64 + l];
            wl.u = wv[2560 + ((ks * 16 + ntg) * 2 + 1) * 64 + l];
            c = MFMA16(pah[ks], wh.b, c);
            c = MFMA16(pal[ks], wh.b, c);
            c = MFMA16(pah[ks], wl.b, c);
        }
        const int u = ntg * 16 + r15;         // hidden unit 0..255
        const float bu = pb1[u];
        const float4 w2 = *(const float4*)&pW2[u * 4];
        #pragma unroll
        for (int j = 0; j < 4; ++j) {         // row j -> query g*4+j
            const float gv = gelu_f(c[j] + bu);
            o[j][0] += gv * w2.x; o[j][1] += gv * w2.y;
            o[j][2] += gv * w2.z; o[j][3] += gv * w2.w;
        }
    }
    #pragma unroll
    for (int j = 0; j < 4; ++j)
        #pragma unroll
        for (int cc = 0; cc < 4; ++cc) {
            o[j][cc] += __shfl_xor(o[j][cc], 1);
            o[j][cc] += __shfl_xor(o[j][cc], 2);
            o[j][cc] += __shfl_xor(o[j][cc], 4);
            o[j][cc] += __shfl_xor(o[j][cc], 8);
        }
    if (r15 == 0) {
        #pragma unroll
        for (int j = 0; j < 4; ++j)
            *(float4*)&spart[w][g * 4 + j][0] =
                make_float4(o[j][0], o[j][1], o[j][2], o[j][3]);
    }
    __syncthreads();

    if (tid < 64) {
        const int qq = tid >> 2, cc = tid & 3;
        const float val = spart[0][qq][cc] + spart[1][qq][cc]
                        + spart[2][qq][cc] + spart[3][qq][cc] + pb2[cc];
        out[(size_t)(blockIdx.x * 16 + qq) * 4 + cc] = val;
    }
}

extern "C" void kernel_launch(void* const* d_in, const int* in_sizes, int n_in,
                              void* d_out, int out_size, void* d_ws, size_t ws_size,
                              hipStream_t stream)
{
    const float* rndata = (const float*)d_in[0];
    const float* qpos   = (const float*)d_in[1];
    const float* latpos = (const float*)d_in[3];
    const int*   edge   = (const int*)d_in[5];
    const float* kW0 = (const float*)d_in[6];
    const float* kb0 = (const float*)d_in[7];
    const float* kW1 = (const float*)d_in[8];
    const float* kb1 = (const float*)d_in[9];
    const float* kW2 = (const float*)d_in[10];
    const float* kb2 = (const float*)d_in[11];
    const float* pW1 = (const float*)d_in[12];
    const float* pb1 = (const float*)d_in[13];
    const float* pW2 = (const float*)d_in[14];
    const float* pb2 = (const float*)d_in[15];
    float* out = (float*)d_out;

    const int E  = in_sizes[5] / 2;   // 1,600,000
    const int Nq = out_size / 4;      // 100,000

    prep_frags<<<208, 256, 0, stream>>>(kW0, kb0, kW1, kW2, pW1, (unsigned short*)d_ws);
    gno_mfma<<<Nq / 16, 256, 0, stream>>>(
        rndata, qpos, latpos, edge + E,
        kb1, kb2, pb1, pW2, pb2,
        (const unsigned short*)d_ws, out);
}